// Round 1
// baseline (255.399 us; speedup 1.0000x reference)
//
#include <hip/hip_runtime.h>
#include <math.h>

// PedestrianDetector: features[B,T,D] fp32 -> dual linear heads (D->12 bbox, D->3 conf),
// sigmoid, top-3-of-3 stable descending sort, threshold 0.5, packed outputs:
//   out[0 .. 196607]        boxes  [B,T,3,4]  (zeroed where invalid)
//   out[196608 .. 245759]   conf   [B,T,3]    (sorted desc)
//   out[245760 .. 294911]   valid  [B,T,3]    (1.0 / 0.0)
// B*T = 16384 rows, D = 2048. Memory-bound: 134 MB feature stream.

#define DCOLS 2048

__global__ __launch_bounds__(512, 4)
void ped_det_kernel(const float* __restrict__ feat,
                    const float* __restrict__ Wb,   // [D,12]
                    const float* __restrict__ bb,   // [12]
                    const float* __restrict__ Wc,   // [D,3]
                    const float* __restrict__ bc,   // [3]
                    float* __restrict__ out,
                    int nrows)
{
    __shared__ float red[8][32][15];

    const int t    = threadIdx.x;
    const int w    = t >> 6;        // wave id 0..7
    const int lane = t & 63;
    const int r    = lane & 31;     // row within block's 32-row group
    const int ks   = lane >> 5;     // K-half within wave
    const int kc   = (w << 1) | ks; // K-chunk 0..15, 128 d each
    const int row  = blockIdx.x * 32 + r;
    const int kbase = kc * 128;

    float acc[15];
#pragma unroll
    for (int j = 0; j < 15; ++j) acc[j] = 0.0f;

    const float* fp = feat + (size_t)row * DCOLS + kbase;

    for (int it = 0; it < 8; ++it) {
        const float* p = fp + it * 16;
        const float4 f0 = *(const float4*)(p + 0);
        const float4 f1 = *(const float4*)(p + 4);
        const float4 f2 = *(const float4*)(p + 8);
        const float4 f3 = *(const float4*)(p + 12);
        const float fv[16] = { f0.x, f0.y, f0.z, f0.w,
                               f1.x, f1.y, f1.z, f1.w,
                               f2.x, f2.y, f2.z, f2.w,
                               f3.x, f3.y, f3.z, f3.w };
        const int dbase = kbase + it * 16;
        const float* wbp = Wb + (size_t)dbase * 12;
        const float* wcp = Wc + (size_t)dbase * 3;
#pragma unroll
        for (int dd = 0; dd < 16; ++dd) {
            const float  v  = fv[dd];
            const float4 b0 = *(const float4*)(wbp + dd * 12 + 0);
            const float4 b1 = *(const float4*)(wbp + dd * 12 + 4);
            const float4 b2 = *(const float4*)(wbp + dd * 12 + 8);
            const float2 cc = *(const float2*)(wcp + dd * 3);
            const float  c2 = wcp[dd * 3 + 2];
            acc[0]  += v * b0.x;  acc[1]  += v * b0.y;
            acc[2]  += v * b0.z;  acc[3]  += v * b0.w;
            acc[4]  += v * b1.x;  acc[5]  += v * b1.y;
            acc[6]  += v * b1.z;  acc[7]  += v * b1.w;
            acc[8]  += v * b2.x;  acc[9]  += v * b2.y;
            acc[10] += v * b2.z;  acc[11] += v * b2.w;
            acc[12] += v * cc.x;  acc[13] += v * cc.y;
            acc[14] += v * c2;
        }
    }

    // fold the two K-halves within each wave
#pragma unroll
    for (int j = 0; j < 15; ++j)
        acc[j] += __shfl_xor(acc[j], 32);

    if (ks == 0) {
#pragma unroll
        for (int j = 0; j < 15; ++j) red[w][r][j] = acc[j];
    }
    __syncthreads();

    // wave 0, lanes 0..31: fold 8 waves, then epilogue
    if (t < 32) {
        const int rr = t;
        float s[15];
#pragma unroll
        for (int j = 0; j < 15; ++j) {
            float v = 0.0f;
#pragma unroll
            for (int ww = 0; ww < 8; ++ww) v += red[ww][rr][j];
            s[j] = v;
        }

        float box[12];
#pragma unroll
        for (int j = 0; j < 12; ++j) box[j] = s[j] + bb[j];
        float conf[3];
#pragma unroll
        for (int a = 0; a < 3; ++a)
            conf[a] = 1.0f / (1.0f + __expf(-(s[12 + a] + bc[a])));

        // stable descending sort of 3 (ties -> lower index first), matches lax.top_k
        int i0 = 0; float m0 = conf[0];
        if (conf[1] > m0) { i0 = 1; m0 = conf[1]; }
        if (conf[2] > m0) { i0 = 2; m0 = conf[2]; }
        const int ra = (i0 == 0) ? 1 : 0;   // smaller remaining index
        const int rb = (i0 == 2) ? 1 : 2;   // larger remaining index
        int i1, i2;
        if (conf[rb] > conf[ra]) { i1 = rb; i2 = ra; }
        else                     { i1 = ra; i2 = rb; }
        const int idx[3] = { i0, i1, i2 };

        const int ro = blockIdx.x * 32 + rr;
        const int conf_off  = nrows * 12;
        const int valid_off = nrows * 15;
        float* boxout  = out + (size_t)ro * 12;
        float* confout = out + conf_off  + (size_t)ro * 3;
        float* valout  = out + valid_off + (size_t)ro * 3;
#pragma unroll
        for (int sl = 0; sl < 3; ++sl) {
            const int   a   = idx[sl];
            const float cv  = conf[a];
            const bool  vld = cv > 0.5f;
            float4 bx;
            bx.x = vld ? box[a * 4 + 0] : 0.0f;
            bx.y = vld ? box[a * 4 + 1] : 0.0f;
            bx.z = vld ? box[a * 4 + 2] : 0.0f;
            bx.w = vld ? box[a * 4 + 3] : 0.0f;
            *(float4*)(boxout + sl * 4) = bx;
            confout[sl] = cv;
            valout[sl]  = vld ? 1.0f : 0.0f;
        }
    }
}

extern "C" void kernel_launch(void* const* d_in, const int* in_sizes, int n_in,
                              void* d_out, int out_size, void* d_ws, size_t ws_size,
                              hipStream_t stream) {
    const float* feat = (const float*)d_in[0];
    const float* Wb   = (const float*)d_in[1];
    const float* bb   = (const float*)d_in[2];
    const float* Wc   = (const float*)d_in[3];
    const float* bc   = (const float*)d_in[4];
    float* out = (float*)d_out;

    const int nrows = in_sizes[0] / DCOLS;     // B*T = 16384
    const int nblocks = nrows / 32;            // 512

    ped_det_kernel<<<dim3(nblocks), dim3(512), 0, stream>>>(
        feat, Wb, bb, Wc, bc, out, nrows);
}

// Round 2
// 241.615 us; speedup vs baseline: 1.0570x; 1.0570x over previous
//
#include <hip/hip_runtime.h>
#include <math.h>

// PedestrianDetector: features[B,T,2048] fp32 -> bbox head (D->12), conf head (D->3),
// sigmoid, stable top-3 sort, threshold 0.5, packed outputs:
//   out[0 .. 12*N)    boxes [N,3,4] (zeroed where invalid)
//   out[12N .. 15N)   conf  [N,3]   (sorted desc)
//   out[15N .. 18N)   valid [N,3]   (1.0/0.0)
// N = B*T = 16384 rows. Memory-bound: 134 MB feature stream (partially L3-resident).
//
// Structure: 512 blocks x 256 threads; block owns 32 rows. K-loop over 16 tiles of
// 128 d. Features staged coalesced (global float4 -> reg -> LDS after compute, classic
// SW pipeline) into padded tile [32][132] (stride 132 = 4 mod 32 -> conflict-free
// ds_read_b128; 132*4 bytes = 16B-aligned). Lane = row (half-wave), so W operands are
// shared across 32 rows per load; W fetched as 15 aligned float4 per 4-d chunk.
// 3-4 blocks/CU co-resident hide stage latency + barriers.

#define DCOLS  2048
#define ROWS   32
#define TILE   128
#define NT     16
#define STRIDE 132

__global__ __launch_bounds__(256)
void ped_det_kernel(const float* __restrict__ feat,
                    const float* __restrict__ Wb,   // [2048][12]
                    const float* __restrict__ bb,   // [12]
                    const float* __restrict__ Wc,   // [2048][3]
                    const float* __restrict__ bc,   // [3]
                    float* __restrict__ out,
                    int nrows)
{
    __shared__ float buf[2][ROWS * STRIDE];     // 2 x 16,896 B = 33.8 KB
    float* P = &buf[0][0];                      // [4][32][16] partials (alias buf A)
    float* S = &buf[0][2048];                   // [32][16] biased sums (alias buf A)

    const int t    = threadIdx.x;
    const int w    = t >> 6;            // wave 0..3
    const int lane = t & 63;
    const int r    = lane & 31;         // local row
    const int h    = lane >> 5;         // d-half within wave
    const int ds   = w * 32 + h * 16;   // this lane's 16-d slice base within a tile
    const size_t row0 = (size_t)blockIdx.x * ROWS;

    float acc[15];
#pragma unroll
    for (int j = 0; j < 15; ++j) acc[j] = 0.0f;

    // ---- prologue: stage tile 0 into buf[0] (coalesced: consecutive threads ->
    // consecutive float4 in global; LDS write pattern is conflict-free)
#pragma unroll
    for (int i = 0; i < 4; ++i) {
        const int c  = i * 256 + t;             // 0..1023 float4-chunks of the tile
        const int rr = c >> 5;                  // row 0..31
        const int cc = (c & 31) * 4;            // col 0..124
        const float4 v = *(const float4*)(feat + (row0 + rr) * DCOLS + cc);
        *(float4*)&buf[0][rr * STRIDE + cc] = v;
    }

    for (int tt = 0; tt < NT; ++tt) {
        const int cur = tt & 1;
        __syncthreads();   // stage(tt) visible to all; compute(tt-1) finished by all

        // ---- issue next tile's global loads (results used only after compute)
        float4 sreg[4];
        if (tt + 1 < NT) {
#pragma unroll
            for (int i = 0; i < 4; ++i) {
                const int c  = i * 256 + t;
                const int rr = c >> 5;
                const int cc = (c & 31) * 4;
                sreg[i] = *(const float4*)(feat + (row0 + rr) * DCOLS +
                                           (size_t)(tt + 1) * TILE + cc);
            }
        }

        // ---- compute tile tt from buf[cur]
        const int tb = tt * TILE;
        const float* fr = &buf[cur][r * STRIDE + ds];
        const float4 f0 = *(const float4*)(fr + 0);
        const float4 f1 = *(const float4*)(fr + 4);
        const float4 f2 = *(const float4*)(fr + 8);
        const float4 f3 = *(const float4*)(fr + 12);
        const float fv[16] = { f0.x, f0.y, f0.z, f0.w,
                               f1.x, f1.y, f1.z, f1.w,
                               f2.x, f2.y, f2.z, f2.w,
                               f3.x, f3.y, f3.z, f3.w };
#pragma unroll
        for (int c = 0; c < 4; ++c) {
            const int d0 = tb + ds + c * 4;              // multiple of 4 -> 16B aligned
            const float4* wbp = (const float4*)(Wb + (size_t)d0 * 12);
            const float4* wcp = (const float4*)(Wc + (size_t)d0 * 3);
            float4 wb[12], wc4[3];
#pragma unroll
            for (int q = 0; q < 12; ++q) wb[q] = wbp[q];
#pragma unroll
            for (int q = 0; q < 3; ++q)  wc4[q] = wcp[q];
            const float* wcf = (const float*)wc4;
#pragma unroll
            for (int j = 0; j < 4; ++j) {
                const float v = fv[c * 4 + j];
                const float4 a0 = wb[j * 3 + 0];
                const float4 a1 = wb[j * 3 + 1];
                const float4 a2 = wb[j * 3 + 2];
                acc[0]  += v * a0.x;  acc[1]  += v * a0.y;
                acc[2]  += v * a0.z;  acc[3]  += v * a0.w;
                acc[4]  += v * a1.x;  acc[5]  += v * a1.y;
                acc[6]  += v * a1.z;  acc[7]  += v * a1.w;
                acc[8]  += v * a2.x;  acc[9]  += v * a2.y;
                acc[10] += v * a2.z;  acc[11] += v * a2.w;
                acc[12] += v * wcf[j * 3 + 0];
                acc[13] += v * wcf[j * 3 + 1];
                acc[14] += v * wcf[j * 3 + 2];
            }
        }

        // ---- commit next tile to the other buffer (vmcnt wait lands here, after compute)
        if (tt + 1 < NT) {
#pragma unroll
            for (int i = 0; i < 4; ++i) {
                const int c  = i * 256 + t;
                const int rr = c >> 5;
                const int cc = (c & 31) * 4;
                *(float4*)&buf[cur ^ 1][rr * STRIDE + cc] = sreg[i];
            }
        }
    }

    // ---- fold the two d-halves within each wave (lanes r and r+32 share a row)
#pragma unroll
    for (int j = 0; j < 15; ++j)
        acc[j] += __shfl_xor(acc[j], 32);

    // ---- write per-wave partials: P[w][r][16]  (buf A free: last read was tile 14)
    if (h == 0) {
        float* pp = &P[(w * 32 + r) * 16];
        *(float4*)(pp + 0)  = make_float4(acc[0],  acc[1],  acc[2],  acc[3]);
        *(float4*)(pp + 4)  = make_float4(acc[4],  acc[5],  acc[6],  acc[7]);
        *(float4*)(pp + 8)  = make_float4(acc[8],  acc[9],  acc[10], acc[11]);
        *(float2*)(pp + 12) = make_float2(acc[12], acc[13]);
        pp[14] = acc[14];
    }
    __syncthreads();

    // ---- combine 4 wave-partials per (row, j) and add bias -> S[row][16]
#pragma unroll
    for (int e = 0; e < 2; ++e) {
        const int u = e * 256 + t;
        if (u < 480) {
            const int row = u / 15;
            const int j   = u % 15;
            float s = P[(0 * 32 + row) * 16 + j] + P[(1 * 32 + row) * 16 + j]
                    + P[(2 * 32 + row) * 16 + j] + P[(3 * 32 + row) * 16 + j];
            s += (j < 12) ? bb[j] : bc[j - 12];
            S[row * 16 + j] = s;
        }
    }
    __syncthreads();

    // ---- epilogue: sigmoid, stable top-3 sort, threshold, packed store (1 thread/row)
    if (t < 32) {
        const int row = t;
        float box[12];
#pragma unroll
        for (int j = 0; j < 12; ++j) box[j] = S[row * 16 + j];
        float conf[3];
#pragma unroll
        for (int a = 0; a < 3; ++a)
            conf[a] = 1.0f / (1.0f + __expf(-S[row * 16 + 12 + a]));

        // stable descending sort of 3 (ties -> lower index), matches lax.top_k
        int i0 = 0; float m0 = conf[0];
        if (conf[1] > m0) { i0 = 1; m0 = conf[1]; }
        if (conf[2] > m0) { i0 = 2; m0 = conf[2]; }
        const int ra = (i0 == 0) ? 1 : 0;
        const int rb = (i0 == 2) ? 1 : 2;
        int i1, i2;
        if (conf[rb] > conf[ra]) { i1 = rb; i2 = ra; }
        else                     { i1 = ra; i2 = rb; }
        const int idx[3] = { i0, i1, i2 };

        const int ro = blockIdx.x * ROWS + row;
        float* boxout  = out + (size_t)ro * 12;
        float* confout = out + (size_t)nrows * 12 + (size_t)ro * 3;
        float* valout  = out + (size_t)nrows * 15 + (size_t)ro * 3;
#pragma unroll
        for (int sl = 0; sl < 3; ++sl) {
            const int   a   = idx[sl];
            const float cv  = conf[a];
            const bool  vld = cv > 0.5f;
            float4 bx;
            bx.x = vld ? box[a * 4 + 0] : 0.0f;
            bx.y = vld ? box[a * 4 + 1] : 0.0f;
            bx.z = vld ? box[a * 4 + 2] : 0.0f;
            bx.w = vld ? box[a * 4 + 3] : 0.0f;
            *(float4*)(boxout + sl * 4) = bx;
            confout[sl] = cv;
            valout[sl]  = vld ? 1.0f : 0.0f;
        }
    }
}

extern "C" void kernel_launch(void* const* d_in, const int* in_sizes, int n_in,
                              void* d_out, int out_size, void* d_ws, size_t ws_size,
                              hipStream_t stream) {
    const float* feat = (const float*)d_in[0];
    const float* Wb   = (const float*)d_in[1];
    const float* bb   = (const float*)d_in[2];
    const float* Wc   = (const float*)d_in[3];
    const float* bc   = (const float*)d_in[4];
    float* out = (float*)d_out;

    const int nrows   = in_sizes[0] / DCOLS;   // 16384
    const int nblocks = nrows / ROWS;          // 512

    ped_det_kernel<<<dim3(nblocks), dim3(256), 0, stream>>>(
        feat, Wb, bb, Wc, bc, out, nrows);
}

// Round 4
// 207.134 us; speedup vs baseline: 1.2330x; 1.1665x over previous
//
#include <hip/hip_runtime.h>
#include <math.h>

// PedestrianDetector: features[B,T,2048] fp32 -> bbox head (D->12), conf head (D->3),
// sigmoid, stable top-3 sort, threshold 0.5, packed outputs:
//   out[0 .. 12N)    boxes [N,3,4] (zeroed where invalid)
//   out[12N .. 15N)  conf  [N,3]   (sorted desc)
//   out[15N .. 18N)  valid [N,3]   (1.0/0.0)
// N = B*T = 16384. Memory-bound: 134 MB feature stream.
//
// v4 = v3 with LDS under 64 KB (v3's 73.7 KB static LDS may have killed the launch).
// Structure: 256 blocks x 1024 threads (16 waves), 1 block/CU, 16 waves/CU (50% occ).
// Block owns 64 rows; wave w owns K-chunk [w*128, w*128+128). lane = row -> W operand
// is wave-uniform: readfirstlane forces W through the SCALAR path (s_load -> SGPR ->
// v_fmac acc, sW, vFeat), so W costs ZERO vector-memory ops. Feature loads are per-lane
// float4 (8 KB apart across the wave) but each lane consumes its whole 64 B line over 4
// back-to-back loads -> line-dense, every line fetched once. No K-loop barriers.
// LDS: P[16][64][15] = 61,440 B; biased sums alias P[0..1023] behind a barrier.

#define DCOLS 2048
#define RPB   64            // rows per block
#define NW    16            // waves per block
#define CHUNK (DCOLS / NW)  // 128 d per wave
#define PSTR  15            // partials row stride (odd -> conflict-free)

__global__ __launch_bounds__(1024, 4)
void ped_det_kernel(const float* __restrict__ feat,
                    const float* __restrict__ Wb,   // [2048][12]
                    const float* __restrict__ bb,   // [12]
                    const float* __restrict__ Wc,   // [2048][3]
                    const float* __restrict__ bc,   // [3]
                    float* __restrict__ out,
                    int nrows)
{
    __shared__ float P[NW * RPB * PSTR];   // 61,440 B
    float* S = P;                          // [64][16] biased sums, aliased after barrier

    const int t    = threadIdx.x;
    const int lane = t & 63;
    const int w    = t >> 6;
    const int wu   = __builtin_amdgcn_readfirstlane(w);  // wave-uniform -> scalar W path
    const int row  = blockIdx.x * RPB + lane;
    const int kb   = wu * CHUNK;

    float acc[15];
#pragma unroll
    for (int j = 0; j < 15; ++j) acc[j] = 0.0f;

    const float* fp = feat + (size_t)row * DCOLS;

#pragma unroll
    for (int g = 0; g < CHUNK / 16; ++g) {      // 8 groups of 16 d
        const int d0 = kb + g * 16;
        // per-lane feature loads: 4 x float4 covering one 64 B line of this row
        const float4 f0 = *(const float4*)(fp + d0 + 0);
        const float4 f1 = *(const float4*)(fp + d0 + 4);
        const float4 f2 = *(const float4*)(fp + d0 + 8);
        const float4 f3 = *(const float4*)(fp + d0 + 12);
        const float fv[16] = { f0.x, f0.y, f0.z, f0.w,
                               f1.x, f1.y, f1.z, f1.w,
                               f2.x, f2.y, f2.z, f2.w,
                               f3.x, f3.y, f3.z, f3.w };
#pragma unroll
        for (int q = 0; q < 4; ++q) {
            const int du = d0 + q * 4;                             // wave-uniform
            const float* __restrict__ wbp = Wb + (size_t)du * 12;  // 48 contiguous floats
            const float* __restrict__ wcp = Wc + (size_t)du * 3;   // 12 contiguous floats
#pragma unroll
            for (int j = 0; j < 4; ++j) {
                const float v = fv[q * 4 + j];
                acc[0]  += v * wbp[j * 12 + 0];
                acc[1]  += v * wbp[j * 12 + 1];
                acc[2]  += v * wbp[j * 12 + 2];
                acc[3]  += v * wbp[j * 12 + 3];
                acc[4]  += v * wbp[j * 12 + 4];
                acc[5]  += v * wbp[j * 12 + 5];
                acc[6]  += v * wbp[j * 12 + 6];
                acc[7]  += v * wbp[j * 12 + 7];
                acc[8]  += v * wbp[j * 12 + 8];
                acc[9]  += v * wbp[j * 12 + 9];
                acc[10] += v * wbp[j * 12 + 10];
                acc[11] += v * wbp[j * 12 + 11];
                acc[12] += v * wcp[j * 3 + 0];
                acc[13] += v * wcp[j * 3 + 1];
                acc[14] += v * wcp[j * 3 + 2];
            }
        }
    }

    // ---- write per-wave partials (stride 15, odd -> <=2-way bank aliasing = free)
    {
        float* pp = &P[(wu * RPB + lane) * PSTR];
#pragma unroll
        for (int j = 0; j < 15; ++j) pp[j] = acc[j];
    }
    __syncthreads();

    // ---- reduce 16 wave-partials per (row, j), add bias -> register s
    float sval = 0.0f;
    int rl = 0, jj = 0;
    if (t < RPB * 15) {                 // u = t = rl*15 + j (consecutive -> conflict-free)
        rl = t / 15;
        jj = t % 15;
        float s = 0.0f;
#pragma unroll
        for (int w2 = 0; w2 < NW; ++w2)
            s += P[(w2 * RPB + rl) * PSTR + jj];
        s += (jj < 12) ? bb[jj] : bc[jj - 12];
        sval = s;
    }
    __syncthreads();                    // all P reads done before S (alias) is written

    if (t < RPB * 15)
        S[rl * 16 + jj] = sval;
    __syncthreads();

    // ---- epilogue: sigmoid, stable top-3 (ties -> lower index), threshold, store
    if (t < RPB) {
        const int r2 = t;
        float box[12];
#pragma unroll
        for (int j = 0; j < 12; ++j) box[j] = S[r2 * 16 + j];
        float conf[3];
#pragma unroll
        for (int a = 0; a < 3; ++a)
            conf[a] = 1.0f / (1.0f + __expf(-S[r2 * 16 + 12 + a]));

        int i0 = 0; float m0 = conf[0];
        if (conf[1] > m0) { i0 = 1; m0 = conf[1]; }
        if (conf[2] > m0) { i0 = 2; m0 = conf[2]; }
        const int ra = (i0 == 0) ? 1 : 0;
        const int rb = (i0 == 2) ? 1 : 2;
        int i1, i2;
        if (conf[rb] > conf[ra]) { i1 = rb; i2 = ra; }
        else                     { i1 = ra; i2 = rb; }
        const int idx[3] = { i0, i1, i2 };

        const int ro = blockIdx.x * RPB + r2;
        float* boxout  = out + (size_t)ro * 12;
        float* confout = out + (size_t)nrows * 12 + (size_t)ro * 3;
        float* valout  = out + (size_t)nrows * 15 + (size_t)ro * 3;
#pragma unroll
        for (int sl = 0; sl < 3; ++sl) {
            const int   a   = idx[sl];
            const float cv  = conf[a];
            const bool  vld = cv > 0.5f;
            float4 bx;
            bx.x = vld ? box[a * 4 + 0] : 0.0f;
            bx.y = vld ? box[a * 4 + 1] : 0.0f;
            bx.z = vld ? box[a * 4 + 2] : 0.0f;
            bx.w = vld ? box[a * 4 + 3] : 0.0f;
            *(float4*)(boxout + sl * 4) = bx;
            confout[sl] = cv;
            valout[sl]  = vld ? 1.0f : 0.0f;
        }
    }
}

extern "C" void kernel_launch(void* const* d_in, const int* in_sizes, int n_in,
                              void* d_out, int out_size, void* d_ws, size_t ws_size,
                              hipStream_t stream) {
    const float* feat = (const float*)d_in[0];
    const float* Wb   = (const float*)d_in[1];
    const float* bb   = (const float*)d_in[2];
    const float* Wc   = (const float*)d_in[3];
    const float* bc   = (const float*)d_in[4];
    float* out = (float*)d_out;

    const int nrows   = in_sizes[0] / DCOLS;   // 16384
    const int nblocks = nrows / RPB;           // 256 -> 1 block/CU

    ped_det_kernel<<<dim3(nblocks), dim3(1024), 0, stream>>>(
        feat, Wb, bb, Wc, bc, out, nrows);
}